// Round 3
// baseline (141.706 us; speedup 1.0000x reference)
//
#include <hip/hip_runtime.h>
#include <math.h>

#define NN 1000000
#define NF4 5000000       // NN*5 float4s in Memory
#define WD 20
#define NB 977            // blocks of 1024 rows
#define PST 1024          // pnrhT column stride
#define MLPB 96           // k_mlp blocks

// d_out layout (floats): out[325] | rw[NN] | ww[NN] | new_memory[NN*20] | nrh[20]
#define OUT_OFF 0
#define RW_OFF  325
#define WW_OFF  1000325
#define NM_OFF  2000325
#define NRH_OFF 22000325

__device__ __forceinline__ float sigmoidf_(float x){ return 1.0f/(1.0f+expf(-x)); }
__device__ __forceinline__ float softplusf_(float x){ return (x>30.f)?x:log1pf(expf(x)); }

// device-scope spin barrier (per-barrier counter, zeroed in k_head each call)
__device__ __forceinline__ void gbar(unsigned* c, unsigned nb){
  __syncthreads();
  if(threadIdx.x==0){
    __hip_atomic_fetch_add(c,1u,__ATOMIC_ACQ_REL,__HIP_MEMORY_SCOPE_AGENT);
    while(__hip_atomic_load(c,__ATOMIC_ACQUIRE,__HIP_MEMORY_SCOPE_AGENT) < nb)
      __builtin_amdgcn_s_sleep(8);
  }
  __syncthreads();
}

// ---------------- K0: controller MLP + head params -> P; zero barrier counters ----------------
// P: kr:0-19 gr:20 sr:21-23 gammar:24 betar:25 knr:26
//    kw:32-51 gw:52 sw:53-55 gammaw:56 betaw:57 knw:58
//    erase:64-83 addraw:84-103 rho:104 ah0:105 ah1:106 addf:112-131
__global__ void k_head(const float* __restrict__ X,
                       const float* __restrict__ W1, const float* __restrict__ b1,
                       const float* __restrict__ W2, const float* __restrict__ b2,
                       const float* __restrict__ Wxi, const float* __restrict__ bxi,
                       const float* __restrict__ Wz, const float* __restrict__ bz,
                       float* __restrict__ P, unsigned* __restrict__ cnt){
  __shared__ float h1[48], h2[72], xi[92], zeta[3];
  int t = threadIdx.x;
  if(t>=96 && t<112) cnt[t-96]=0u;
  if(t<48){ float a=b1[t]; const float* w=W1+t*14; for(int c=0;c<14;c++) a+=X[c]*w[c]; h1[t]=a; }
  __syncthreads();
  if(t<72){ float a=b2[t]; const float* w=W2+t*48; for(int c=0;c<48;c++) a+=h1[c]*w[c]; h2[t]=a; }
  __syncthreads();
  if(t<92){ float a=bxi[t]; const float* w=Wxi+t*72; for(int c=0;c<72;c++) a+=h2[c]*w[c]; xi[t]=a; }
  else if(t<95){ int z=t-92; float a=bz[z]; const float* w=Wz+z*72; for(int c=0;c<72;c++) a+=h2[c]*w[c]; zeta[z]=a; }
  __syncthreads();
  if(t<20){
    P[0+t]  = tanhf(xi[t]);
    P[32+t] = tanhf(xi[26+t]);
    P[64+t] = sigmoidf_(xi[52+t]);
    P[84+t] = tanhf(xi[72+t]);
  }
  if(t==32){
    const float* p = xi;
    float g=sigmoidf_(p[20]);
    float a0=p[21],a1=p[22],a2=p[23];
    float mx=fmaxf(a0,fmaxf(a1,a2));
    float e0=expf(a0-mx),e1=expf(a1-mx),e2=expf(a2-mx),es=e0+e1+e2;
    float gamma=1.0f+softplusf_(p[24]);
    float beta=softplusf_(p[25]);
    float n2=0.f; for(int j=0;j<20;j++){ float ke=tanhf(p[j])+1e-16f; n2+=ke*ke; }
    P[20]=g; P[21]=e0/es; P[22]=e1/es; P[23]=e2/es; P[24]=gamma; P[25]=beta;
    P[26]=fmaxf(sqrtf(n2),1e-8f);
  }
  if(t==33){
    const float* p = xi+26;
    float g=sigmoidf_(p[20]);
    float a0=p[21],a1=p[22],a2=p[23];
    float mx=fmaxf(a0,fmaxf(a1,a2));
    float e0=expf(a0-mx),e1=expf(a1-mx),e2=expf(a2-mx),es=e0+e1+e2;
    float gamma=1.0f+softplusf_(p[24]);
    float beta=softplusf_(p[25]);
    float n2=0.f; for(int j=0;j<20;j++){ float ke=tanhf(p[j])+1e-16f; n2+=ke*ke; }
    P[52]=g; P[53]=e0/es; P[54]=e1/es; P[55]=e2/es; P[56]=gamma; P[57]=beta;
    P[58]=fmaxf(sqrtf(n2),1e-8f);
  }
  if(t==34){
    P[104]=sigmoidf_(zeta[0]);
    float mx=fmaxf(zeta[1],zeta[2]);
    float e1=expf(zeta[1]-mx), e2=expf(zeta[2]-mx);
    P[105]=e1/(e1+e2); P[106]=e2/(e1+e2);
  }
}

// ------- K1: cosine scores (LDS-transposed M read) + per-block {max, local expsum} -------
__global__ __launch_bounds__(256) void k_scores(const float* __restrict__ M, const float* __restrict__ P,
                         float2* __restrict__ sc2, float4* __restrict__ pms){
  __shared__ float4 ld[1280];   // 20 KB
  int t=threadIdx.x, b=blockIdx.x;
  float kr[20], kw[20];
#pragma unroll
  for(int j=0;j<20;j++){ kr[j]=P[j]+1e-16f; kw[j]=P[32+j]+1e-16f; }
  float betar=P[25], betaw=P[57], knr=P[26], knw=P[58];
  const float4* Mf4=(const float4*)M;
  float sR[4], sW[4];
  for(int p=0;p<4;p++){
    int rb=b*1024+p*256;
    size_t f4b=(size_t)rb*5;
#pragma unroll
    for(int k=0;k<5;k++){
      size_t idx=f4b+(size_t)(k*256+t);
      ld[k*256+t] = (idx<NF4)?Mf4[idx]:make_float4(0.f,0.f,0.f,0.f);
    }
    __syncthreads();
    int i=rb+t;
    float srv=-3.0e38f, swv=-3.0e38f;
    if(i<NN){
      float dr=0.f,dw=0.f,n2=0.f;
#pragma unroll
      for(int q=0;q<5;q++){
        float4 v=ld[t*5+q];
        float m0=v.x+1e-16f,m1=v.y+1e-16f,m2=v.z+1e-16f,m3=v.w+1e-16f;
        dr+=m0*kr[4*q]+m1*kr[4*q+1]+m2*kr[4*q+2]+m3*kr[4*q+3];
        dw+=m0*kw[4*q]+m1*kw[4*q+1]+m2*kw[4*q+2]+m3*kw[4*q+3];
        n2+=m0*m0+m1*m1+m2*m2+m3*m3;
      }
      float nm=fmaxf(sqrtf(n2),1e-8f);
      srv=betar*(dr/(nm*knr));
      swv=betaw*(dw/(nm*knw));
      sc2[i]=make_float2(srv,swv);
    }
    sR[p]=srv; sW[p]=swv;
    __syncthreads();
  }
  // reductions (reuse ld as scratch)
  float* r1=(float*)ld; float* r2=r1+256;
  double* d1=(double*)(r1+512); double* d2=d1+256;
  float lm1=fmaxf(fmaxf(sR[0],sR[1]),fmaxf(sR[2],sR[3]));
  float lm2=fmaxf(fmaxf(sW[0],sW[1]),fmaxf(sW[2],sW[3]));
  r1[t]=lm1; r2[t]=lm2; __syncthreads();
  for(int o=128;o>0;o>>=1){ if(t<o){ r1[t]=fmaxf(r1[t],r1[t+o]); r2[t]=fmaxf(r2[t],r2[t+o]); } __syncthreads(); }
  float mb1=r1[0], mb2=r2[0]; __syncthreads();
  double s1=0.0,s2=0.0;
#pragma unroll
  for(int p=0;p<4;p++){ s1+=(double)expf(sR[p]-mb1); s2+=(double)expf(sW[p]-mb2); }
  d1[t]=s1; d2[t]=s2; __syncthreads();
  for(int o=128;o>0;o>>=1){ if(t<o){ d1[t]+=d1[t+o]; d2[t]+=d2[t+o]; } __syncthreads(); }
  if(t==0) pms[b]=make_float4(mb1,mb2,(float)d1[0],(float)d2[0]);
}

// ------- K2: interpolate+shift+pow; Z partials; fused rw@M (LDS-transposed) -------
__global__ __launch_bounds__(256) void k_shift(const float2* __restrict__ sc2,
                        const float* __restrict__ wpr, const float* __restrict__ wpw,
                        const float* __restrict__ M, const float* __restrict__ P,
                        const float4* __restrict__ pms,
                        float* __restrict__ w_r_out, float* __restrict__ w_w_out,
                        double* __restrict__ pZ, double* __restrict__ pnrhT){
  __shared__ float4 ld[1280];
  __shared__ float bmS[4];
  float* r1=(float*)ld; float* r2=r1+256;
  double* d1=(double*)(r1+512); double* d2=d1+256;
  float* wsum=(float*)(d2+256);  // [4][20]
  int t=threadIdx.x, b=blockIdx.x;
  // redundant global (m,S) reduction over NB partials
  float4 v4[4];
#pragma unroll
  for(int k=0;k<4;k++){
    int idx=t+k*256;
    v4[k] = (idx<NB) ? pms[idx] : make_float4(-3.0e38f,-3.0e38f,0.f,0.f);
  }
  float lm1=fmaxf(fmaxf(v4[0].x,v4[1].x),fmaxf(v4[2].x,v4[3].x));
  float lm2=fmaxf(fmaxf(v4[0].y,v4[1].y),fmaxf(v4[2].y,v4[3].y));
  r1[t]=lm1; r2[t]=lm2; __syncthreads();
  for(int o=128;o>0;o>>=1){ if(t<o){ r1[t]=fmaxf(r1[t],r1[t+o]); r2[t]=fmaxf(r2[t],r2[t+o]); } __syncthreads(); }
  if(t==0){ bmS[0]=r1[0]; bmS[1]=r2[0]; } __syncthreads();
  float mr=bmS[0], mw=bmS[1];
  double s1=0.0,s2=0.0;
#pragma unroll
  for(int k=0;k<4;k++){
    s1 += (double)v4[k].z * (double)expf(v4[k].x-mr);
    s2 += (double)v4[k].w * (double)expf(v4[k].y-mw);
  }
  d1[t]=s1; d2[t]=s2; __syncthreads();
  for(int o=128;o>0;o>>=1){ if(t<o){ d1[t]+=d1[t+o]; d2[t]+=d2[t+o]; } __syncthreads(); }
  if(t==0){ bmS[2]=(float)d1[0]; bmS[3]=(float)d2[0]; } __syncthreads();
  float Sr=bmS[2], Sw=bmS[3];
  float gr=P[20], s0r=P[21], s1r=P[22], s2r=P[23], gar=P[24];
  float gw=P[52], s0w=P[53], s1w=P[54], s2w=P[55], gaw=P[56];
  float omgr=1.0f-gr, omgw=1.0f-gw;
  const float4* Mf4=(const float4*)M;
  float acc[20];
#pragma unroll
  for(int j=0;j<20;j++) acc[j]=0.f;
  double zr=0.0, zw=0.0;
  for(int p=0;p<4;p++){
    int rb=b*1024+p*256;
    size_t f4b=(size_t)rb*5;
#pragma unroll
    for(int k=0;k<5;k++){
      size_t idx=f4b+(size_t)(k*256+t);
      ld[k*256+t] = (idx<NF4)?Mf4[idx]:make_float4(0.f,0.f,0.f,0.f);
    }
    __syncthreads();
    int i=rb+t;
    if(i<NN){
      int im1=(i==0)?(NN-1):(i-1);
      int ip1=(i==NN-1)?0:(i+1);
      float2 scm=sc2[im1], sc0=sc2[i], scp=sc2[ip1];
      float wgrm = gr*(expf(scm.x-mr)/Sr) + omgr*wpr[im1];
      float wgr0 = gr*(expf(sc0.x-mr)/Sr) + omgr*wpr[i  ];
      float wgrp = gr*(expf(scp.x-mr)/Sr) + omgr*wpr[ip1];
      float wgwm = gw*(expf(scm.y-mw)/Sw) + omgw*wpw[im1];
      float wgw0 = gw*(expf(sc0.y-mw)/Sw) + omgw*wpw[i  ];
      float wgwp = gw*(expf(scp.y-mw)/Sw) + omgw*wpw[ip1];
      float wr = powf(s0r*wgrm + s1r*wgr0 + s2r*wgrp, gar);
      float ww = powf(s0w*wgwm + s1w*wgw0 + s2w*wgwp, gaw);
      w_r_out[i]=wr; w_w_out[i]=ww;
      zr+=(double)wr; zw+=(double)ww;
#pragma unroll
      for(int q=0;q<5;q++){
        float4 mv=ld[t*5+q];
        acc[4*q+0]+=wr*mv.x; acc[4*q+1]+=wr*mv.y; acc[4*q+2]+=wr*mv.z; acc[4*q+3]+=wr*mv.w;
      }
    }
    __syncthreads();
  }
  d1[t]=zr; d2[t]=zw; __syncthreads();
  for(int o=128;o>0;o>>=1){ if(t<o){ d1[t]+=d1[t+o]; d2[t]+=d2[t+o]; } __syncthreads(); }
  if(t==0){ pZ[2*b]=d1[0]; pZ[2*b+1]=d2[0]; }
  __syncthreads();
#pragma unroll
  for(int j=0;j<20;j++){
    for(int off=32;off>0;off>>=1) acc[j]+=__shfl_down(acc[j],off,64);
  }
  int wave=t>>6, lane=t&63;
  if(lane==0){
#pragma unroll
    for(int j=0;j<20;j++) wsum[wave*20+j]=acc[j];
  }
  __syncthreads();
  if(t<20){
    double s=(double)wsum[0*20+t]+(double)wsum[1*20+t]+(double)wsum[2*20+t]+(double)wsum[3*20+t];
    pnrhT[(size_t)t*PST+b]=s;
  }
}

// ------- K3: merged MLP chain (nrh + 4 layers + fin) with spin barriers -------
__global__ __launch_bounds__(256) void k_mlp(const double* __restrict__ pZ, const double* __restrict__ pnrhT,
                      const float* __restrict__ read_head,
                      const float* __restrict__ aW1,const float* __restrict__ ab1,
                      const float* __restrict__ aW2,const float* __restrict__ ab2,
                      const float* __restrict__ aW3,const float* __restrict__ ab3,
                      const float* __restrict__ aW4,const float* __restrict__ ab4,
                      const float* __restrict__ mW1,const float* __restrict__ mb1,
                      const float* __restrict__ mW2,const float* __restrict__ mb2,
                      const float* __restrict__ mW3,const float* __restrict__ mb3,
                      const float* __restrict__ mW4,const float* __restrict__ mb4,
                      const float* __restrict__ Wv, const float* __restrict__ bv,
                      float* __restrict__ P, float* __restrict__ out,
                      float* __restrict__ in40, float* __restrict__ F,
                      double* __restrict__ Sd, unsigned* __restrict__ cnt){
  __shared__ double dd[256];
  __shared__ float A[325], B[325], red[256], sc[2];
  int t=threadIdx.x, b=blockIdx.x;
  int wid=b*4+(t>>6), lane=t&63;
  float *h1a=F,      *h1m=F+110;
  float *h2a=F+220,  *h2m=F+410;
  float *h3a=F+600,  *h3m=F+870;
  float *h4a=F+1140, *h4m=F+1465;
  // Phase 0: Z reduces + nrh columns + in40
  if(b<20){
    double a=0.0;
    for(int idx=t; idx<NB; idx+=256) a+=pZ[2*idx];
    dd[t]=a; __syncthreads();
    for(int o=128;o>0;o>>=1){ if(t<o) dd[t]+=dd[t+o]; __syncthreads(); }
    double Zr=dd[0]; __syncthreads();
    double c=0.0;
    for(int idx=t; idx<NB; idx+=256) c+=pnrhT[(size_t)b*PST+idx];
    dd[t]=c; __syncthreads();
    for(int o=128;o>0;o>>=1){ if(t<o) dd[t]+=dd[t+o]; __syncthreads(); }
    if(t==0){
      float nv=(float)(dd[0]/(Zr+1e-16));
      in40[20+b]=nv; out[NRH_OFF+b]=nv;
    }
  } else if(b==20){
    double a=0.0,c=0.0;
    for(int idx=t; idx<NB; idx+=256){ a+=pZ[2*idx]; c+=pZ[2*idx+1]; }
    dd[t]=a; __syncthreads();
    for(int o=128;o>0;o>>=1){ if(t<o) dd[t]+=dd[t+o]; __syncthreads(); }
    if(t==0) Sd[0]=dd[0];
    __syncthreads();
    dd[t]=c; __syncthreads();
    for(int o=128;o>0;o>>=1){ if(t<o) dd[t]+=dd[t+o]; __syncthreads(); }
    if(t==0) Sd[1]=dd[0];
  } else if(b==21){
    if(t<20) in40[t]=read_head[t];
  }
  gbar(cnt+0,MLPB);
  // Phase 1: layer1, 220 rows, K=40
  if(wid<220){
    int net=(wid>=110), r=wid-net*110;
    const float* W=net?mW1:aW1; const float* bb=net?mb1:ab1; float* o=net?h1m:h1a;
    const float* w=W+(size_t)r*40;
    float a=0.f; for(int c=lane;c<40;c+=64) a+=w[c]*in40[c];
    for(int off=32;off>0;off>>=1) a+=__shfl_down(a,off,64);
    if(lane==0) o[r]=fmaxf(a+bb[r],0.f);
  }
  gbar(cnt+1,MLPB);
  // Phase 2: layer2, 380 rows, K=110
  if(wid<380){
    int net=(wid>=190), r=wid-net*190;
    const float* W=net?mW2:aW2; const float* bb=net?mb2:ab2;
    const float* in=net?h1m:h1a; float* o=net?h2m:h2a;
    const float* w=W+(size_t)r*110;
    float a=0.f; for(int c=lane;c<110;c+=64) a+=w[c]*in[c];
    for(int off=32;off>0;off>>=1) a+=__shfl_down(a,off,64);
    if(lane==0) o[r]=fmaxf(a+bb[r],0.f);
  }
  gbar(cnt+2,MLPB);
  // Phase 3: layer3, 540 rows, K=190
  for(int r0=wid; r0<540; r0+=MLPB*4){
    int net=(r0>=270), r=r0-net*270;
    const float* W=net?mW3:aW3; const float* bb=net?mb3:ab3;
    const float* in=net?h2m:h2a; float* o=net?h3m:h3a;
    const float* w=W+(size_t)r*190;
    float a=0.f; for(int c=lane;c<190;c+=64) a+=w[c]*in[c];
    for(int off=32;off>0;off>>=1) a+=__shfl_down(a,off,64);
    if(lane==0) o[r]=fmaxf(a+bb[r],0.f);
  }
  gbar(cnt+3,MLPB);
  // Phase 4: layer4, 650 rows, K=270, no relu
  for(int r0=wid; r0<650; r0+=MLPB*4){
    int net=(r0>=325), r=r0-net*325;
    const float* W=net?mW4:aW4; const float* bb=net?mb4:ab4;
    const float* in=net?h3m:h3a; float* o=net?h4m:h4a;
    const float* w=W+(size_t)r*270;
    float a=0.f; for(int c=lane;c<270;c+=64) a+=w[c]*in[c];
    for(int off=32;off>0;off>>=1) a+=__shfl_down(a,off,64);
    if(lane==0) o[r]=a+bb[r];
  }
  gbar(cnt+4,MLPB);
  // Phase 5: block 0 — softmaxes, combine, out, v, add_final
  if(b==0){
    // net A softmax
    float x0=h4a[t];
    float x1=(t<69)?h4a[256+t]:-3.0e38f;
    red[t]=fmaxf(x0,x1); __syncthreads();
    for(int o=128;o>0;o>>=1){ if(t<o) red[t]=fmaxf(red[t],red[t+o]); __syncthreads(); }
    if(t==0) sc[0]=red[0]; __syncthreads();
    float e0=expf(x0-sc[0]), e1=(t<69)?expf(x1-sc[0]):0.f;
    red[t]=e0+e1; __syncthreads();
    for(int o=128;o>0;o>>=1){ if(t<o) red[t]+=red[t+o]; __syncthreads(); }
    if(t==0) sc[1]=red[0]; __syncthreads();
    A[t]=e0/sc[1]; if(t<69) A[256+t]=e1/sc[1];
    __syncthreads();
    // net M softmax
    float y0=h4m[t];
    float y1=(t<69)?h4m[256+t]:-3.0e38f;
    red[t]=fmaxf(y0,y1); __syncthreads();
    for(int o=128;o>0;o>>=1){ if(t<o) red[t]=fmaxf(red[t],red[t+o]); __syncthreads(); }
    if(t==0) sc[0]=red[0]; __syncthreads();
    float f0=expf(y0-sc[0]), f1=(t<69)?expf(y1-sc[0]):0.f;
    red[t]=f0+f1; __syncthreads();
    for(int o=128;o>0;o>>=1){ if(t<o) red[t]+=red[t+o]; __syncthreads(); }
    if(t==0) sc[1]=red[0]; __syncthreads();
    B[t]=f0/sc[1]; if(t<69) B[256+t]=f1/sc[1];
    __syncthreads();
    float ah0=P[105], ah1=P[106];
    float ov0=ah0*A[t]+ah1*B[t];
    out[OUT_OFF+t]=ov0; A[t]=ov0;
    if(t<69){ float ov1=ah0*A[256+t]+ah1*B[256+t]; out[OUT_OFF+256+t]=ov1; A[256+t]=ov1; }
    __syncthreads();
    int wv=t>>6;
    float rho=P[104];
    for(int r=wv; r<20; r+=4){
      const float* w=Wv+(size_t)r*325;
      float a=0.f;
      for(int c=lane;c<325;c+=64) a+=w[c]*A[c];
      for(int off=32;off>0;off>>=1) a+=__shfl_down(a,off,64);
      if(lane==0){
        float vv=a+bv[r];
        P[112+r]=rho*P[84+r]+(1.0f-rho)*vv;
      }
    }
  }
}

// ------- K4: normalize rw/ww in place + new_memory (LDS-staged both directions) -------
__global__ __launch_bounds__(256) void k_memupd(const float* __restrict__ M,
                         float* __restrict__ w_r, float* __restrict__ w_w,
                         const float* __restrict__ P, const double* __restrict__ Sd,
                         float* __restrict__ nm){
  __shared__ float4 ld[1280];
  int t=threadIdx.x, b=blockIdx.x;
  float er[20], af[20];
#pragma unroll
  for(int j=0;j<20;j++){ er[j]=P[64+j]; af[j]=P[112+j]; }
  float Zr=(float)Sd[0]+1e-16f, Zw=(float)Sd[1]+1e-16f;
  const float4* Mf4=(const float4*)M;
  float4* nmf4=(float4*)nm;
  for(int p=0;p<4;p++){
    int rb=b*1024+p*256;
    size_t f4b=(size_t)rb*5;
#pragma unroll
    for(int k=0;k<5;k++){
      size_t idx=f4b+(size_t)(k*256+t);
      if(idx<NF4) ld[k*256+t]=Mf4[idx];
    }
    __syncthreads();
    int i=rb+t;
    if(i<NN){
      float wrn=w_r[i]/Zr;
      float wwn=w_w[i]/Zw;
      w_r[i]=wrn; w_w[i]=wwn;
#pragma unroll
      for(int q=0;q<5;q++){
        float4 v=ld[t*5+q];
        float4 o;
        o.x=v.x*(1.0f-wwn*er[4*q+0])+wwn*af[4*q+0];
        o.y=v.y*(1.0f-wwn*er[4*q+1])+wwn*af[4*q+1];
        o.z=v.z*(1.0f-wwn*er[4*q+2])+wwn*af[4*q+2];
        o.w=v.w*(1.0f-wwn*er[4*q+3])+wwn*af[4*q+3];
        ld[t*5+q]=o;
      }
    }
    __syncthreads();
#pragma unroll
    for(int k=0;k<5;k++){
      size_t idx=f4b+(size_t)(k*256+t);
      if(idx<NF4) nmf4[idx]=ld[k*256+t];
    }
    __syncthreads();
  }
}

extern "C" void kernel_launch(void* const* d_in, const int* in_sizes, int n_in,
                              void* d_out, int out_size, void* d_ws, size_t ws_size,
                              hipStream_t stream) {
  const float* X    =(const float*)d_in[0];
  const float* rwp  =(const float*)d_in[1];
  const float* wwp  =(const float*)d_in[2];
  const float* Mem  =(const float*)d_in[3];
  const float* rhd  =(const float*)d_in[4];
  const float* W1   =(const float*)d_in[5];
  const float* b1   =(const float*)d_in[6];
  const float* W2   =(const float*)d_in[7];
  const float* b2   =(const float*)d_in[8];
  const float* Wxi  =(const float*)d_in[9];
  const float* bxi  =(const float*)d_in[10];
  const float* Wz   =(const float*)d_in[11];
  const float* bz   =(const float*)d_in[12];
  const float* Wv   =(const float*)d_in[13];
  const float* bv   =(const float*)d_in[14];
  const float* aW1  =(const float*)d_in[15];
  const float* ab1  =(const float*)d_in[16];
  const float* aW2  =(const float*)d_in[17];
  const float* ab2  =(const float*)d_in[18];
  const float* aW3  =(const float*)d_in[19];
  const float* ab3  =(const float*)d_in[20];
  const float* aW4  =(const float*)d_in[21];
  const float* ab4  =(const float*)d_in[22];
  const float* mW1  =(const float*)d_in[23];
  const float* mb1  =(const float*)d_in[24];
  const float* mW2  =(const float*)d_in[25];
  const float* mb2  =(const float*)d_in[26];
  const float* mW3  =(const float*)d_in[27];
  const float* mb3  =(const float*)d_in[28];
  const float* mW4  =(const float*)d_in[29];
  const float* mb4  =(const float*)d_in[30];

  float* out = (float*)d_out;
  char* ws = (char*)d_ws;
  float*    P     = (float*)   (ws + 0);        // 256 floats
  unsigned* cnt   = (unsigned*)(ws + 1024);     // 16 counters
  double*   Sd    = (double*)  (ws + 2048);     // Z_r, Z_w
  float*    in40  = (float*)   (ws + 2304);
  float*    F     = (float*)   (ws + 4096);     // MLP activations (~1.8K floats)
  float4*   pms   = (float4*)  (ws + 16384);    // NB float4
  double*   pZ    = (double*)  (ws + 32768);    // NB*2
  double*   pnrhT = (double*)  (ws + 65536);    // 20*PST (160 KB) -> ends 229376

  float2* sc2 = (float2*)(out + NM_OFF);   // scores staged in dead nm region
  float*  w_r = out + RW_OFF;              // unnormalized until k_memupd
  float*  w_w = out + WW_OFF;
  float*  nm  = out + NM_OFF;

  k_head<<<1,128,0,stream>>>(X,W1,b1,W2,b2,Wxi,bxi,Wz,bz,P,cnt);
  k_scores<<<NB,256,0,stream>>>(Mem,P,sc2,pms);
  k_shift<<<NB,256,0,stream>>>(sc2,rwp,wwp,Mem,P,pms,w_r,w_w,pZ,pnrhT);
  k_mlp<<<MLPB,256,0,stream>>>(pZ,pnrhT,rhd,
                               aW1,ab1,aW2,ab2,aW3,ab3,aW4,ab4,
                               mW1,mb1,mW2,mb2,mW3,mb3,mW4,mb4,
                               Wv,bv,P,out,in40,F,Sd,cnt);
  k_memupd<<<NB,256,0,stream>>>(Mem,w_r,w_w,P,Sd,nm);
}

// Round 4
// 116.461 us; speedup vs baseline: 1.2168x; 1.2168x over previous
//
#include <hip/hip_runtime.h>
#include <math.h>

#define NN 1000000
#define NF4 5000000       // NN*5 float4s in Memory
#define WD 20
#define NB 977            // blocks of 1024 rows
#define PST 1024          // pnrhT column stride

// d_out layout (floats): out[325] | rw[NN] | ww[NN] | new_memory[NN*20] | nrh[20]
#define OUT_OFF 0
#define RW_OFF  325
#define WW_OFF  1000325
#define NM_OFF  2000325
#define NRH_OFF 22000325

__device__ __forceinline__ float sigmoidf_(float x){ return 1.0f/(1.0f+expf(-x)); }
__device__ __forceinline__ float softplusf_(float x){ return (x>30.f)?x:log1pf(expf(x)); }

// ------- K1: controller-head prologue (redundant per block) + cosine scores -------
// P layout: kr:0-19 gr:20 sr:21-23 gammar:24 betar:25 knr:26
//           kw:32-51 gw:52 sw:53-55 gammaw:56 betaw:57 knw:58
//           erase:64-83 addraw:84-103 rho:104 ah0:105 ah1:106 addf:112-131
__global__ __launch_bounds__(256) void k_scores(
    const float* __restrict__ X,
    const float* __restrict__ W1, const float* __restrict__ b1,
    const float* __restrict__ W2, const float* __restrict__ b2,
    const float* __restrict__ Wxi, const float* __restrict__ bxi,
    const float* __restrict__ Wz, const float* __restrict__ bz,
    const float* __restrict__ M, float* __restrict__ Pg,
    float2* __restrict__ sc2, float4* __restrict__ pms){
  __shared__ float4 ld[1280];   // 20 KB
  __shared__ float h1[48], h2[72], xi[95], sP[132];
  int t=threadIdx.x, b=blockIdx.x;
  // --- head prologue (identical in every block; block 0 publishes) ---
  if(t<48){ float a=b1[t]; const float* w=W1+t*14; for(int c=0;c<14;c++) a+=X[c]*w[c]; h1[t]=a; }
  __syncthreads();
  if(t<72){ float a=b2[t]; const float* w=W2+t*48; for(int c=0;c<48;c++) a+=h1[c]*w[c]; h2[t]=a; }
  __syncthreads();
  if(t<92){ float a=bxi[t]; const float* w=Wxi+t*72; for(int c=0;c<72;c++) a+=h2[c]*w[c]; xi[t]=a; }
  else if(t<95){ int z=t-92; float a=bz[z]; const float* w=Wz+z*72; for(int c=0;c<72;c++) a+=h2[c]*w[c]; xi[92+z]=a; }
  __syncthreads();
  if(t<20){
    sP[0+t]  = tanhf(xi[t]);
    sP[32+t] = tanhf(xi[26+t]);
    sP[64+t] = sigmoidf_(xi[52+t]);
    sP[84+t] = tanhf(xi[72+t]);
  }
  if(t==32){
    const float* p = xi;
    float g=sigmoidf_(p[20]);
    float a0=p[21],a1=p[22],a2=p[23];
    float mx=fmaxf(a0,fmaxf(a1,a2));
    float e0=expf(a0-mx),e1=expf(a1-mx),e2=expf(a2-mx),es=e0+e1+e2;
    float gamma=1.0f+softplusf_(p[24]);
    float beta=softplusf_(p[25]);
    float n2=0.f; for(int j=0;j<20;j++){ float ke=tanhf(p[j])+1e-16f; n2+=ke*ke; }
    sP[20]=g; sP[21]=e0/es; sP[22]=e1/es; sP[23]=e2/es; sP[24]=gamma; sP[25]=beta;
    sP[26]=fmaxf(sqrtf(n2),1e-8f);
  }
  if(t==33){
    const float* p = xi+26;
    float g=sigmoidf_(p[20]);
    float a0=p[21],a1=p[22],a2=p[23];
    float mx=fmaxf(a0,fmaxf(a1,a2));
    float e0=expf(a0-mx),e1=expf(a1-mx),e2=expf(a2-mx),es=e0+e1+e2;
    float gamma=1.0f+softplusf_(p[24]);
    float beta=softplusf_(p[25]);
    float n2=0.f; for(int j=0;j<20;j++){ float ke=tanhf(p[j])+1e-16f; n2+=ke*ke; }
    sP[52]=g; sP[53]=e0/es; sP[54]=e1/es; sP[55]=e2/es; sP[56]=gamma; sP[57]=beta;
    sP[58]=fmaxf(sqrtf(n2),1e-8f);
  }
  if(t==34){
    sP[104]=sigmoidf_(xi[92]);
    float mx=fmaxf(xi[93],xi[94]);
    float e1=expf(xi[93]-mx), e2=expf(xi[94]-mx);
    sP[105]=e1/(e1+e2); sP[106]=e2/(e1+e2);
  }
  __syncthreads();
  if(b==0 && t<132) Pg[t]=sP[t];
  float kr[20], kw[20];
#pragma unroll
  for(int j=0;j<20;j++){ kr[j]=sP[j]+1e-16f; kw[j]=sP[32+j]+1e-16f; }
  float betar=sP[25], betaw=sP[57], knr=sP[26], knw=sP[58];
  // --- streaming scores ---
  const float4* Mf4=(const float4*)M;
  float sR[4], sW[4];
  for(int p=0;p<4;p++){
    int rb=b*1024+p*256;
    size_t f4b=(size_t)rb*5;
#pragma unroll
    for(int k=0;k<5;k++){
      size_t idx=f4b+(size_t)(k*256+t);
      ld[k*256+t] = (idx<NF4)?Mf4[idx]:make_float4(0.f,0.f,0.f,0.f);
    }
    __syncthreads();
    int i=rb+t;
    float srv=-3.0e38f, swv=-3.0e38f;
    if(i<NN){
      float dr=0.f,dw=0.f,n2=0.f;
#pragma unroll
      for(int q=0;q<5;q++){
        float4 v=ld[t*5+q];
        float m0=v.x+1e-16f,m1=v.y+1e-16f,m2=v.z+1e-16f,m3=v.w+1e-16f;
        dr+=m0*kr[4*q]+m1*kr[4*q+1]+m2*kr[4*q+2]+m3*kr[4*q+3];
        dw+=m0*kw[4*q]+m1*kw[4*q+1]+m2*kw[4*q+2]+m3*kw[4*q+3];
        n2+=m0*m0+m1*m1+m2*m2+m3*m3;
      }
      float nm=fmaxf(sqrtf(n2),1e-8f);
      srv=betar*(dr/(nm*knr));
      swv=betaw*(dw/(nm*knw));
      sc2[i]=make_float2(srv,swv);
    }
    sR[p]=srv; sW[p]=swv;
    __syncthreads();
  }
  // reductions (reuse ld as scratch)
  float* r1=(float*)ld; float* r2=r1+256;
  double* d1=(double*)(r1+512); double* d2=d1+256;
  float lm1=fmaxf(fmaxf(sR[0],sR[1]),fmaxf(sR[2],sR[3]));
  float lm2=fmaxf(fmaxf(sW[0],sW[1]),fmaxf(sW[2],sW[3]));
  r1[t]=lm1; r2[t]=lm2; __syncthreads();
  for(int o=128;o>0;o>>=1){ if(t<o){ r1[t]=fmaxf(r1[t],r1[t+o]); r2[t]=fmaxf(r2[t],r2[t+o]); } __syncthreads(); }
  float mb1=r1[0], mb2=r2[0]; __syncthreads();
  double s1=0.0,s2=0.0;
#pragma unroll
  for(int p=0;p<4;p++){ s1+=(double)expf(sR[p]-mb1); s2+=(double)expf(sW[p]-mb2); }
  d1[t]=s1; d2[t]=s2; __syncthreads();
  for(int o=128;o>0;o>>=1){ if(t<o){ d1[t]+=d1[t+o]; d2[t]+=d2[t+o]; } __syncthreads(); }
  if(t==0) pms[b]=make_float4(mb1,mb2,(float)d1[0],(float)d2[0]);
}

// ------- K2: interpolate+shift+pow; Z partials; fused rw@M (LDS-transposed) -------
__global__ __launch_bounds__(256) void k_shift(const float2* __restrict__ sc2,
                        const float* __restrict__ wpr, const float* __restrict__ wpw,
                        const float* __restrict__ M, const float* __restrict__ P,
                        const float4* __restrict__ pms,
                        float* __restrict__ w_r_out, float* __restrict__ w_w_out,
                        double* __restrict__ pZ, double* __restrict__ pnrhT){
  __shared__ float4 ld[1280];
  __shared__ float bmS[4];
  float* r1=(float*)ld; float* r2=r1+256;
  double* d1=(double*)(r1+512); double* d2=d1+256;
  float* wsum=(float*)(d2+256);  // [4][20]
  int t=threadIdx.x, b=blockIdx.x;
  // redundant global (m,S) reduction over NB partials
  float4 v4[4];
#pragma unroll
  for(int k=0;k<4;k++){
    int idx=t+k*256;
    v4[k] = (idx<NB) ? pms[idx] : make_float4(-3.0e38f,-3.0e38f,0.f,0.f);
  }
  float lm1=fmaxf(fmaxf(v4[0].x,v4[1].x),fmaxf(v4[2].x,v4[3].x));
  float lm2=fmaxf(fmaxf(v4[0].y,v4[1].y),fmaxf(v4[2].y,v4[3].y));
  r1[t]=lm1; r2[t]=lm2; __syncthreads();
  for(int o=128;o>0;o>>=1){ if(t<o){ r1[t]=fmaxf(r1[t],r1[t+o]); r2[t]=fmaxf(r2[t],r2[t+o]); } __syncthreads(); }
  if(t==0){ bmS[0]=r1[0]; bmS[1]=r2[0]; } __syncthreads();
  float mr=bmS[0], mw=bmS[1];
  double s1=0.0,s2=0.0;
#pragma unroll
  for(int k=0;k<4;k++){
    s1 += (double)v4[k].z * (double)expf(v4[k].x-mr);
    s2 += (double)v4[k].w * (double)expf(v4[k].y-mw);
  }
  d1[t]=s1; d2[t]=s2; __syncthreads();
  for(int o=128;o>0;o>>=1){ if(t<o){ d1[t]+=d1[t+o]; d2[t]+=d2[t+o]; } __syncthreads(); }
  if(t==0){ bmS[2]=(float)d1[0]; bmS[3]=(float)d2[0]; } __syncthreads();
  float Sr=bmS[2], Sw=bmS[3];
  float gr=P[20], s0r=P[21], s1r=P[22], s2r=P[23], gar=P[24];
  float gw=P[52], s0w=P[53], s1w=P[54], s2w=P[55], gaw=P[56];
  float omgr=1.0f-gr, omgw=1.0f-gw;
  const float4* Mf4=(const float4*)M;
  float acc[20];
#pragma unroll
  for(int j=0;j<20;j++) acc[j]=0.f;
  double zr=0.0, zw=0.0;
  for(int p=0;p<4;p++){
    int rb=b*1024+p*256;
    size_t f4b=(size_t)rb*5;
#pragma unroll
    for(int k=0;k<5;k++){
      size_t idx=f4b+(size_t)(k*256+t);
      ld[k*256+t] = (idx<NF4)?Mf4[idx]:make_float4(0.f,0.f,0.f,0.f);
    }
    __syncthreads();
    int i=rb+t;
    if(i<NN){
      int im1=(i==0)?(NN-1):(i-1);
      int ip1=(i==NN-1)?0:(i+1);
      float2 scm=sc2[im1], sc0=sc2[i], scp=sc2[ip1];
      float wgrm = gr*(expf(scm.x-mr)/Sr) + omgr*wpr[im1];
      float wgr0 = gr*(expf(sc0.x-mr)/Sr) + omgr*wpr[i  ];
      float wgrp = gr*(expf(scp.x-mr)/Sr) + omgr*wpr[ip1];
      float wgwm = gw*(expf(scm.y-mw)/Sw) + omgw*wpw[im1];
      float wgw0 = gw*(expf(sc0.y-mw)/Sw) + omgw*wpw[i  ];
      float wgwp = gw*(expf(scp.y-mw)/Sw) + omgw*wpw[ip1];
      float wr = powf(s0r*wgrm + s1r*wgr0 + s2r*wgrp, gar);
      float ww = powf(s0w*wgwm + s1w*wgw0 + s2w*wgwp, gaw);
      w_r_out[i]=wr; w_w_out[i]=ww;
      zr+=(double)wr; zw+=(double)ww;
#pragma unroll
      for(int q=0;q<5;q++){
        float4 mv=ld[t*5+q];
        acc[4*q+0]+=wr*mv.x; acc[4*q+1]+=wr*mv.y; acc[4*q+2]+=wr*mv.z; acc[4*q+3]+=wr*mv.w;
      }
    }
    __syncthreads();
  }
  d1[t]=zr; d2[t]=zw; __syncthreads();
  for(int o=128;o>0;o>>=1){ if(t<o){ d1[t]+=d1[t+o]; d2[t]+=d2[t+o]; } __syncthreads(); }
  if(t==0){ pZ[2*b]=d1[0]; pZ[2*b+1]=d2[0]; }
  __syncthreads();
#pragma unroll
  for(int j=0;j<20;j++){
    for(int off=32;off>0;off>>=1) acc[j]+=__shfl_down(acc[j],off,64);
  }
  int wave=t>>6, lane=t&63;
  if(lane==0){
#pragma unroll
    for(int j=0;j<20;j++) wsum[wave*20+j]=acc[j];
  }
  __syncthreads();
  if(t<20){
    double s=(double)wsum[0*20+t]+(double)wsum[1*20+t]+(double)wsum[2*20+t]+(double)wsum[3*20+t];
    pnrhT[(size_t)t*PST+b]=s;
  }
}

// ------- K3: Z reduce (redundant per block) + nrh column reduce; builds in40 -------
__global__ __launch_bounds__(256) void k_nrh(const double* __restrict__ pZ, const double* __restrict__ pnrhT,
                      const float* __restrict__ read_head,
                      float* __restrict__ in40, float* __restrict__ out, double* __restrict__ Sd){
  __shared__ double dd[256];
  __shared__ double bZ[2];
  int t=threadIdx.x, j=blockIdx.x;
  double a=0.0,c=0.0;
  for(int idx=t; idx<NB; idx+=256){ a+=pZ[2*idx]; c+=pZ[2*idx+1]; }
  dd[t]=a; __syncthreads();
  for(int o=128;o>0;o>>=1){ if(t<o) dd[t]+=dd[t+o]; __syncthreads(); }
  if(t==0) bZ[0]=dd[0]; __syncthreads();
  dd[t]=c; __syncthreads();
  for(int o=128;o>0;o>>=1){ if(t<o) dd[t]+=dd[t+o]; __syncthreads(); }
  if(t==0) bZ[1]=dd[0]; __syncthreads();
  if(j==0 && t==0){ Sd[0]=bZ[0]; Sd[1]=bZ[1]; }
  double s=0.0;
  for(int idx=t; idx<NB; idx+=256) s+=pnrhT[(size_t)j*PST+idx];
  dd[t]=s; __syncthreads();
  for(int o=128;o>0;o>>=1){ if(t<o) dd[t]+=dd[t+o]; __syncthreads(); }
  if(t==0){
    float nv=(float)(dd[0]/(bZ[0]+1e-16));
    in40[20+j]=nv; out[NRH_OFF+j]=nv;
    in40[j]=read_head[j];
  }
}

// ------- generic MLP layer: wave-per-row, both nets via grid halves -------
__global__ __launch_bounds__(256) void k_layer(const float* __restrict__ Wa, const float* __restrict__ ba,
                        const float* __restrict__ Wm, const float* __restrict__ bm,
                        const float* __restrict__ inA, const float* __restrict__ inM,
                        float* __restrict__ oA, float* __restrict__ oM,
                        int rows, int K, int RB, int doRelu){
  int net = (blockIdx.x >= RB) ? 1 : 0;
  const float* W = net ? Wm : Wa;
  const float* bb = net ? bm : ba;
  const float* in = net ? inM : inA;
  float* o = net ? oM : oA;
  int wave=threadIdx.x>>6, lane=threadIdx.x&63;
  int r=(blockIdx.x - net*RB)*4 + wave;
  if(r>=rows) return;
  const float* w = W + (size_t)r*K;
  float a=0.f;
  for(int c=lane; c<K; c+=64) a += w[c]*in[c];
  for(int off=32;off>0;off>>=1) a += __shfl_down(a,off,64);
  if(lane==0){
    float vv=a+bb[r];
    o[r]= doRelu ? fmaxf(vv,0.f) : vv;
  }
}

// ------- K8: softmax both nets, combine, out, v, add_final -------
__global__ __launch_bounds__(512) void k_fin(const float* __restrict__ h4a, const float* __restrict__ h4m,
                      const float* __restrict__ Wv, const float* __restrict__ bv,
                      float* __restrict__ P, float* __restrict__ out){
  __shared__ float red[512];
  __shared__ float A[325], B[325];
  __shared__ float sc[2];
  int t=threadIdx.x;
  float la=(t<325)?h4a[t]:-3.0e38f;
  red[t]=la; __syncthreads();
  for(int o=256;o>0;o>>=1){ if(t<o) red[t]=fmaxf(red[t],red[t+o]); __syncthreads(); }
  if(t==0) sc[0]=red[0]; __syncthreads();
  float ea=(t<325)?expf(la-sc[0]):0.f;
  red[t]=ea; __syncthreads();
  for(int o=256;o>0;o>>=1){ if(t<o) red[t]+=red[t+o]; __syncthreads(); }
  if(t==0) sc[1]=red[0]; __syncthreads();
  if(t<325) A[t]=ea/sc[1];
  __syncthreads();
  float lm=(t<325)?h4m[t]:-3.0e38f;
  red[t]=lm; __syncthreads();
  for(int o=256;o>0;o>>=1){ if(t<o) red[t]=fmaxf(red[t],red[t+o]); __syncthreads(); }
  if(t==0) sc[0]=red[0]; __syncthreads();
  float em=(t<325)?expf(lm-sc[0]):0.f;
  red[t]=em; __syncthreads();
  for(int o=256;o>0;o>>=1){ if(t<o) red[t]+=red[t+o]; __syncthreads(); }
  if(t==0) sc[1]=red[0]; __syncthreads();
  if(t<325) B[t]=em/sc[1];
  __syncthreads();
  float ah0=P[105], ah1=P[106];
  if(t<325){ float ov=ah0*A[t]+ah1*B[t]; out[OUT_OFF+t]=ov; A[t]=ov; }
  __syncthreads();
  int wave=t>>6, lane=t&63;
  for(int r=wave; r<20; r+=8){
    const float* w=Wv+(size_t)r*325;
    float a=0.f;
    for(int c=lane;c<325;c+=64) a+=w[c]*A[c];
    for(int off=32;off>0;off>>=1) a+=__shfl_down(a,off,64);
    if(lane==0){
      float vv=a+bv[r];
      float rho=P[104];
      P[112+r]=rho*P[84+r]+(1.0f-rho)*vv;
    }
  }
}

// ------- K9: normalize rw/ww in place + new_memory (LDS-staged both directions) -------
__global__ __launch_bounds__(256) void k_memupd(const float* __restrict__ M,
                         float* __restrict__ w_r, float* __restrict__ w_w,
                         const float* __restrict__ P, const double* __restrict__ Sd,
                         float* __restrict__ nm){
  __shared__ float4 ld[1280];
  int t=threadIdx.x, b=blockIdx.x;
  float er[20], af[20];
#pragma unroll
  for(int j=0;j<20;j++){ er[j]=P[64+j]; af[j]=P[112+j]; }
  float Zr=(float)Sd[0]+1e-16f, Zw=(float)Sd[1]+1e-16f;
  const float4* Mf4=(const float4*)M;
  float4* nmf4=(float4*)nm;
  for(int p=0;p<4;p++){
    int rb=b*1024+p*256;
    size_t f4b=(size_t)rb*5;
#pragma unroll
    for(int k=0;k<5;k++){
      size_t idx=f4b+(size_t)(k*256+t);
      if(idx<NF4) ld[k*256+t]=Mf4[idx];
    }
    __syncthreads();
    int i=rb+t;
    if(i<NN){
      float wrn=w_r[i]/Zr;
      float wwn=w_w[i]/Zw;
      w_r[i]=wrn; w_w[i]=wwn;
#pragma unroll
      for(int q=0;q<5;q++){
        float4 v=ld[t*5+q];
        float4 o;
        o.x=v.x*(1.0f-wwn*er[4*q+0])+wwn*af[4*q+0];
        o.y=v.y*(1.0f-wwn*er[4*q+1])+wwn*af[4*q+1];
        o.z=v.z*(1.0f-wwn*er[4*q+2])+wwn*af[4*q+2];
        o.w=v.w*(1.0f-wwn*er[4*q+3])+wwn*af[4*q+3];
        ld[t*5+q]=o;
      }
    }
    __syncthreads();
#pragma unroll
    for(int k=0;k<5;k++){
      size_t idx=f4b+(size_t)(k*256+t);
      if(idx<NF4) nmf4[idx]=ld[k*256+t];
    }
    __syncthreads();
  }
}

extern "C" void kernel_launch(void* const* d_in, const int* in_sizes, int n_in,
                              void* d_out, int out_size, void* d_ws, size_t ws_size,
                              hipStream_t stream) {
  const float* X    =(const float*)d_in[0];
  const float* rwp  =(const float*)d_in[1];
  const float* wwp  =(const float*)d_in[2];
  const float* Mem  =(const float*)d_in[3];
  const float* rhd  =(const float*)d_in[4];
  const float* W1   =(const float*)d_in[5];
  const float* b1   =(const float*)d_in[6];
  const float* W2   =(const float*)d_in[7];
  const float* b2   =(const float*)d_in[8];
  const float* Wxi  =(const float*)d_in[9];
  const float* bxi  =(const float*)d_in[10];
  const float* Wz   =(const float*)d_in[11];
  const float* bz   =(const float*)d_in[12];
  const float* Wv   =(const float*)d_in[13];
  const float* bv   =(const float*)d_in[14];
  const float* aW1  =(const float*)d_in[15];
  const float* ab1  =(const float*)d_in[16];
  const float* aW2  =(const float*)d_in[17];
  const float* ab2  =(const float*)d_in[18];
  const float* aW3  =(const float*)d_in[19];
  const float* ab3  =(const float*)d_in[20];
  const float* aW4  =(const float*)d_in[21];
  const float* ab4  =(const float*)d_in[22];
  const float* mW1  =(const float*)d_in[23];
  const float* mb1  =(const float*)d_in[24];
  const float* mW2  =(const float*)d_in[25];
  const float* mb2  =(const float*)d_in[26];
  const float* mW3  =(const float*)d_in[27];
  const float* mb3  =(const float*)d_in[28];
  const float* mW4  =(const float*)d_in[29];
  const float* mb4  =(const float*)d_in[30];

  float* out = (float*)d_out;
  char* ws = (char*)d_ws;
  float*    P     = (float*)   (ws + 0);        // 256 floats
  double*   Sd    = (double*)  (ws + 2048);     // Z_r, Z_w
  float*    in40  = (float*)   (ws + 2304);
  float*    F     = (float*)   (ws + 4096);     // MLP activations
  float4*   pms   = (float4*)  (ws + 16384);    // NB float4
  double*   pZ    = (double*)  (ws + 32768);    // NB*2
  double*   pnrhT = (double*)  (ws + 65536);    // 20*PST (160 KB)
  float *h1a=F,      *h1m=F+110;
  float *h2a=F+220,  *h2m=F+410;
  float *h3a=F+600,  *h3m=F+870;
  float *h4a=F+1140, *h4m=F+1465;

  float2* sc2 = (float2*)(out + NM_OFF);   // scores staged in dead nm region
  float*  w_r = out + RW_OFF;              // unnormalized until k_memupd
  float*  w_w = out + WW_OFF;
  float*  nm  = out + NM_OFF;

  k_scores<<<NB,256,0,stream>>>(X,W1,b1,W2,b2,Wxi,bxi,Wz,bz,Mem,P,sc2,pms);
  k_shift<<<NB,256,0,stream>>>(sc2,rwp,wwp,Mem,P,pms,w_r,w_w,pZ,pnrhT);
  k_nrh<<<20,256,0,stream>>>(pZ,pnrhT,rhd,in40,out,Sd);
  k_layer<<<56,256,0,stream>>>(aW1,ab1,mW1,mb1,in40,in40,h1a,h1m,110,40,28,1);
  k_layer<<<96,256,0,stream>>>(aW2,ab2,mW2,mb2,h1a,h1m,h2a,h2m,190,110,48,1);
  k_layer<<<136,256,0,stream>>>(aW3,ab3,mW3,mb3,h2a,h2m,h3a,h3m,270,190,68,1);
  k_layer<<<164,256,0,stream>>>(aW4,ab4,mW4,mb4,h3a,h3m,h4a,h4m,325,270,82,0);
  k_fin<<<1,512,0,stream>>>(h4a,h4m,Wv,bv,P,out);
  k_memupd<<<NB,256,0,stream>>>(Mem,w_r,w_w,P,Sd,nm);
}